// Round 5
// baseline (354.865 us; speedup 1.0000x reference)
//
#include <hip/hip_runtime.h>

#define N_NODES 50000
#define N_EDGES 800000
#define D_IN 128
#define HIDDEN 64
#define N_CLASSES 2
#define NBUK 782        // ceil(50000/64) buckets of 64 nodes
#define BCAP 2048       // bucket capacity (avg fill 1024, sigma 32 -> 32-sigma margin)

// ---------------- pass A: bin edges by dst>>6 (append-local writes) ----------------

__global__ __launch_bounds__(256) void k_binA(const int4* __restrict__ src4,
                                              const int4* __restrict__ dst4,
                                              int* __restrict__ bcnt,
                                              int2* __restrict__ ebin) {
    int t = blockIdx.x * 256 + threadIdx.x;
    if (t >= N_EDGES / 4) return;
    int4 s = src4[t];
    int4 d = dst4[t];
    int b0 = d.x >> 6, b1 = d.y >> 6, b2 = d.z >> 6, b3 = d.w >> 6;
    int p0 = atomicAdd(&bcnt[b0], 1);
    int p1 = atomicAdd(&bcnt[b1], 1);
    int p2 = atomicAdd(&bcnt[b2], 1);
    int p3 = atomicAdd(&bcnt[b3], 1);
    ebin[b0 * BCAP + p0] = make_int2(s.x, d.x);
    ebin[b1 * BCAP + p1] = make_int2(s.y, d.y);
    ebin[b2 * BCAP + p2] = make_int2(s.z, d.z);
    ebin[b3 * BCAP + p3] = make_int2(s.w, d.w);
}

// ---------------- scan 782 bucket counts -> bucket_off (one small block) ----------------

__global__ __launch_bounds__(256) void k_bucket_scan(const int* __restrict__ bcnt,
                                                     int* __restrict__ bucket_off,
                                                     int* __restrict__ row_ptr) {
    __shared__ int part[256];
    int t = threadIdx.x;
    int v0 = bcnt[t * 4 + 0], v1 = bcnt[t * 4 + 1], v2 = bcnt[t * 4 + 2], v3 = bcnt[t * 4 + 3];
    int tot = v0 + v1 + v2 + v3;
    part[t] = tot;
    __syncthreads();
    for (int off = 1; off < 256; off <<= 1) {
        int p = (t >= off) ? part[t - off] : 0;
        __syncthreads();
        part[t] += p;
        __syncthreads();
    }
    int run = (t == 0) ? 0 : part[t - 1];
    bucket_off[t * 4 + 0] = run; run += v0;
    bucket_off[t * 4 + 1] = run; run += v1;
    bucket_off[t * 4 + 2] = run; run += v2;
    bucket_off[t * 4 + 3] = run; run += v3;
    if (t == 255) bucket_off[1024] = run;
    if (t == 0) row_ptr[N_NODES] = N_EDGES;
}

// ---------------- per-bucket degree count + node scan -> row_ptr, dinv ----------------
// 4 waves/block, one wave per bucket. LDS counting (no global atomics).
__global__ __launch_bounds__(256) void k_bucket_deg(const int2* __restrict__ ebin,
                                                    const int* __restrict__ bcnt,
                                                    const int* __restrict__ bucket_off,
                                                    int* __restrict__ row_ptr,
                                                    float* __restrict__ dinv) {
    __shared__ int cnt[4][64];
    int wave = threadIdx.x >> 6;
    int lane = threadIdx.x & 63;
    int b = blockIdx.x * 4 + wave;
    if (b >= NBUK) return;
    cnt[wave][lane] = 0;
    __syncthreads();
    int c = bcnt[b];
    const int2* eb = &ebin[b * BCAP];
    for (int i = lane; i < c; i += 64) atomicAdd(&cnt[wave][eb[i].y & 63], 1);
    __syncthreads();
    int deg = cnt[wave][lane];
    // inclusive wave prefix scan
    int sum = deg;
#pragma unroll
    for (int off = 1; off < 64; off <<= 1) {
        int v = __shfl_up(sum, off, 64);
        if (lane >= off) sum += v;
    }
    int node = b * 64 + lane;
    if (node < N_NODES) {
        row_ptr[node] = bucket_off[b] + sum - deg;
        dinv[node] = rsqrtf((float)(deg + 1));  // +1 self-loop
    }
}

// ---------------- pass B: scatter within bucket via LDS cursors ----------------
// rec = (src, dinv[src]); the dinv[dst] factor is applied in the agg kernels.
__global__ __launch_bounds__(256) void k_binB(const int2* __restrict__ ebin,
                                              const int* __restrict__ bcnt,
                                              const int* __restrict__ row_ptr,
                                              const float* __restrict__ dinv,
                                              int2* __restrict__ rec) {
    __shared__ int cur[64];
    int b = blockIdx.x;
    int tid = threadIdx.x;
    if (tid < 64) {
        int node = b * 64 + tid;
        cur[tid] = (node < N_NODES) ? row_ptr[node] : 0;
    }
    __syncthreads();
    int c = bcnt[b];
    const int2* eb = &ebin[b * BCAP];
    for (int i = tid; i < c; i += 256) {
        int2 e = eb[i];
        float ws = dinv[e.x];
        int pos = atomicAdd(&cur[e.y & 63], 1);
        rec[pos] = make_int2(e.x, __float_as_int(ws));
    }
}

// ---------------- GEMM1: h = x @ W1 ----------------

__device__ inline void fma4(float4& acc, float s, const float4& w) {
    acc.x = fmaf(s, w.x, acc.x);
    acc.y = fmaf(s, w.y, acc.y);
    acc.z = fmaf(s, w.z, acc.z);
    acc.w = fmaf(s, w.w, acc.w);
}

__global__ __launch_bounds__(256) void k_gemm1(
    const float* __restrict__ x, const float* __restrict__ W1, float* __restrict__ h)
{
    __shared__ float Ws[D_IN * HIDDEN];  // [k][col] 32KB
    __shared__ float xs[64 * D_IN];      // [row][k^swz] 32KB
    const int tid = threadIdx.x;
    const int row0 = blockIdx.x * 64;

    const float4* W4 = (const float4*)W1;
    float4* Ws4 = (float4*)Ws;
    for (int i = tid; i < D_IN * HIDDEN / 4; i += 256) Ws4[i] = W4[i];

    for (int i = tid; i < 64 * D_IN / 4; i += 256) {
        int r = i >> 5;
        int k4 = (i & 31) << 2;
        float4 v = make_float4(0.f, 0.f, 0.f, 0.f);
        int grow = row0 + r;
        if (grow < N_NODES) v = *(const float4*)&x[grow * D_IN + k4];
        int sw = ((r >> 2) & 1) << 4;
        *(float4*)&xs[r * D_IN + (k4 ^ sw)] = v;
    }
    __syncthreads();

    const int c4 = (tid & 15) * 4;
    const int r4 = (tid >> 4) * 4;
    float4 acc[4];
#pragma unroll
    for (int j = 0; j < 4; j++) acc[j] = make_float4(0.f, 0.f, 0.f, 0.f);

    for (int k = 0; k < D_IN; k += 4) {
        float4 w0 = *(const float4*)&Ws[(k + 0) * HIDDEN + c4];
        float4 w1 = *(const float4*)&Ws[(k + 1) * HIDDEN + c4];
        float4 w2 = *(const float4*)&Ws[(k + 2) * HIDDEN + c4];
        float4 w3 = *(const float4*)&Ws[(k + 3) * HIDDEN + c4];
        float4 a[4];
#pragma unroll
        for (int j = 0; j < 4; j++) {
            int r = r4 + j;
            int sw = ((r >> 2) & 1) << 4;
            a[j] = *(const float4*)&xs[r * D_IN + (k ^ sw)];
        }
#pragma unroll
        for (int j = 0; j < 4; j++) {
            fma4(acc[j], a[j].x, w0);
            fma4(acc[j], a[j].y, w1);
            fma4(acc[j], a[j].z, w2);
            fma4(acc[j], a[j].w, w3);
        }
    }

#pragma unroll
    for (int j = 0; j < 4; j++) {
        int grow = row0 + r4 + j;
        if (grow < N_NODES) *(float4*)&h[grow * HIDDEN + c4] = acc[j];
    }
}

// ---------------- fused: pull-aggregate layer1 + relu + layer2 + self-loop init ----------------
// acc_total = (sum_e v_e*dinv_src + h_node*di) * di
__global__ __launch_bounds__(256) void k_agg1_l2(
    const float* __restrict__ h, const int* __restrict__ row_ptr,
    const int2* __restrict__ rec, const float* __restrict__ dinv,
    const float* __restrict__ b1, const float* __restrict__ W2,
    const float* __restrict__ b2, float* __restrict__ z, float* __restrict__ out)
{
    int node = blockIdx.x * 4 + (threadIdx.x >> 6);  // grid 12500, exact
    int lane = threadIdx.x & 63;

    float di = dinv[node];
    float acc = h[node * HIDDEN + lane] * di;  // self-loop (x di again at end)

    int beg = row_ptr[node];
    int end = row_ptr[node + 1];

    for (int base = beg; base < end; base += 64) {
        int n = end - base;
        if (n > 64) n = 64;
        int2 r = make_int2(0, 0);  // pad lanes: src=0, w=0 -> harmless fma
        if (lane < n) r = rec[base + lane];
        int n4 = (n + 3) & ~3;
        for (int e = 0; e < n4; e += 4) {
            int   s0 = __shfl(r.x, e + 0, 64);
            float w0 = __int_as_float(__shfl(r.y, e + 0, 64));
            int   s1 = __shfl(r.x, e + 1, 64);
            float w1 = __int_as_float(__shfl(r.y, e + 1, 64));
            int   s2 = __shfl(r.x, e + 2, 64);
            float w2 = __int_as_float(__shfl(r.y, e + 2, 64));
            int   s3 = __shfl(r.x, e + 3, 64);
            float w3 = __int_as_float(__shfl(r.y, e + 3, 64));
            float v0 = h[(size_t)s0 * HIDDEN + lane];
            float v1 = h[(size_t)s1 * HIDDEN + lane];
            float v2 = h[(size_t)s2 * HIDDEN + lane];
            float v3 = h[(size_t)s3 * HIDDEN + lane];
            acc = fmaf(v0, w0, acc);
            acc = fmaf(v1, w1, acc);
            acc = fmaf(v2, w2, acc);
            acc = fmaf(v3, w3, acc);
        }
    }
    acc *= di;

    // layer 2: y = relu(acc + b1); p = y @ W2 (wave-reduce)
    float y = fmaxf(acc + b1[lane], 0.0f);
    float p0 = y * W2[lane * N_CLASSES + 0];
    float p1 = y * W2[lane * N_CLASSES + 1];
#pragma unroll
    for (int off = 32; off > 0; off >>= 1) {
        p0 += __shfl_down(p0, off, 64);
        p1 += __shfl_down(p1, off, 64);
    }
    if (lane == 0) {
        float s2 = di * di;
        z[node * 2 + 0] = p0;
        z[node * 2 + 1] = p1;
        out[node * 2 + 0] = fmaf(p0, s2, b2[0]);  // self-loop + bias init
        out[node * 2 + 1] = fmaf(p1, s2, b2[1]);
    }
}

// ---------------- pull-aggregate layer 2: wave per node, lane-parallel edges ----------------

__global__ __launch_bounds__(256) void k_agg2(
    const float* __restrict__ z, const int* __restrict__ row_ptr,
    const int2* __restrict__ rec, const float* __restrict__ dinv,
    float* __restrict__ out)
{
    int node = blockIdx.x * 4 + (threadIdx.x >> 6);  // grid 12500, exact
    int lane = threadIdx.x & 63;
    int beg = row_ptr[node];
    int end = row_ptr[node + 1];
    float a0 = 0.f, a1 = 0.f;
    for (int idx = beg + lane; idx < end; idx += 64) {
        int2 r = rec[idx];
        float w = __int_as_float(r.y);
        float2 v = *(const float2*)&z[r.x * 2];
        a0 = fmaf(v.x, w, a0);
        a1 = fmaf(v.y, w, a1);
    }
#pragma unroll
    for (int off = 32; off > 0; off >>= 1) {
        a0 += __shfl_down(a0, off, 64);
        a1 += __shfl_down(a1, off, 64);
    }
    if (lane == 0) {
        float di = dinv[node];
        out[node * 2 + 0] += a0 * di;  // out pre-initialized with self-loop + bias
        out[node * 2 + 1] += a1 * di;
    }
}

// ---------------- launch ----------------

extern "C" void kernel_launch(void* const* d_in, const int* in_sizes, int n_in,
                              void* d_out, int out_size, void* d_ws, size_t ws_size,
                              hipStream_t stream) {
    const float* x  = (const float*)d_in[0];
    const int* ei   = (const int*)d_in[1];
    const float* W1 = (const float*)d_in[2];
    const float* b1 = (const float*)d_in[3];
    const float* W2 = (const float*)d_in[4];
    const float* b2 = (const float*)d_in[5];
    float* out = (float*)d_out;

    const int* src = ei;
    const int* dst = ei + N_EDGES;

    // workspace layout (4-byte units), ~20.0 MB
    int*   bcnt       = (int*)d_ws;                      // [0, 1024)     (782 used, pad zeroed)
    int*   bucket_off = (int*)d_ws + 1024;               // [1024, 2080)  (1025 used)
    float* dinv       = (float*)d_ws + 2080;             // [2080, 52256)
    int*   row_ptr    = (int*)d_ws + 52256;              // [52256, 102368)
    int2*  rec        = (int2*)((int*)d_ws + 102368);    // 800000 int2
    int2*  ebin       = (int2*)((int*)d_ws + 1702368);   // 782*2048 int2 (aliased by h)
    float* h          = (float*)d_ws + 1702368;          // 3.2M floats, written after ebin is dead
    float* z          = (float*)d_ws + 4905440;          // 100k floats

    hipMemsetAsync(bcnt, 0, 1024 * sizeof(int), stream);
    k_binA<<<(N_EDGES / 4 + 255) / 256, 256, 0, stream>>>((const int4*)src, (const int4*)dst, bcnt, ebin);
    k_bucket_scan<<<1, 256, 0, stream>>>(bcnt, bucket_off, row_ptr);
    k_bucket_deg<<<(NBUK + 3) / 4, 256, 0, stream>>>(ebin, bcnt, bucket_off, row_ptr, dinv);
    k_binB<<<NBUK, 256, 0, stream>>>(ebin, bcnt, row_ptr, dinv, rec);
    k_gemm1<<<(N_NODES + 63) / 64, 256, 0, stream>>>(x, W1, h);
    k_agg1_l2<<<N_NODES / 4, 256, 0, stream>>>(h, row_ptr, rec, dinv, b1, W2, b2, z, out);
    k_agg2<<<N_NODES / 4, 256, 0, stream>>>(z, row_ptr, rec, dinv, out);
}

// Round 6
// 184.532 us; speedup vs baseline: 1.9231x; 1.9231x over previous
//
#include <hip/hip_runtime.h>

#define N_NODES 50000
#define N_EDGES 800000
#define D_IN 128
#define HIDDEN 64
#define N_CLASSES 2
#define NBUK 782        // ceil(50000/64) buckets of 64 nodes
#define NBUK_P 784      // padded row stride for hist arrays
#define NBLK 782        // edge-chunk blocks: 782*1024 >= 800000

// ---------------- phase 1: per-chunk LDS histogram over dst buckets ----------------

__global__ __launch_bounds__(256) void k_hist(const int4* __restrict__ dst4,
                                              int* __restrict__ bhist) {
    __shared__ int hist[NBUK];
    int t = threadIdx.x;
    for (int i = t; i < NBUK; i += 256) hist[i] = 0;
    __syncthreads();
    int idx = blockIdx.x * 256 + t;
    if (idx < N_EDGES / 4) {
        int4 d = dst4[idx];
        atomicAdd(&hist[d.x >> 6], 1);
        atomicAdd(&hist[d.y >> 6], 1);
        atomicAdd(&hist[d.z >> 6], 1);
        atomicAdd(&hist[d.w >> 6], 1);
    }
    __syncthreads();
    for (int i = t; i < NBUK; i += 256) bhist[blockIdx.x * NBUK_P + i] = hist[i];
}

// ---------------- phase 2: column scan (per bucket, over chunks) ----------------
// exc[blk][b] = sum of bhist[blk'<blk][b]; colsum[b] = total count of bucket b.

__global__ __launch_bounds__(256) void k_colscan(const int* __restrict__ bhist,
                                                 int* __restrict__ exc,
                                                 int* __restrict__ colsum) {
    __shared__ int part[256];
    int b = blockIdx.x;   // bucket
    int t = threadIdx.x;
    int v[4];
    int s = 0;
#pragma unroll
    for (int i = 0; i < 4; i++) {
        int blk = t * 4 + i;
        v[i] = (blk < NBLK) ? bhist[blk * NBUK_P + b] : 0;
        s += v[i];
    }
    part[t] = s;
    __syncthreads();
    for (int off = 1; off < 256; off <<= 1) {
        int p = (t >= off) ? part[t - off] : 0;
        __syncthreads();
        part[t] += p;
        __syncthreads();
    }
    int run = (t == 0) ? 0 : part[t - 1];
#pragma unroll
    for (int i = 0; i < 4; i++) {
        int blk = t * 4 + i;
        if (blk < NBLK) exc[blk * NBUK_P + b] = run;
        run += v[i];
    }
    if (t == 255) colsum[b] = run;
}

// ---------------- phase 3: scan 782 bucket totals -> bucket_off (one block) ----------------

__global__ __launch_bounds__(256) void k_bucket_scan(const int* __restrict__ colsum,
                                                     int* __restrict__ bucket_off,
                                                     int* __restrict__ row_ptr) {
    __shared__ int part[256];
    int t = threadIdx.x;
    int v[4];
    int s = 0;
#pragma unroll
    for (int i = 0; i < 4; i++) {
        int idx = t * 4 + i;
        v[i] = (idx < NBUK) ? colsum[idx] : 0;
        s += v[i];
    }
    part[t] = s;
    __syncthreads();
    for (int off = 1; off < 256; off <<= 1) {
        int p = (t >= off) ? part[t - off] : 0;
        __syncthreads();
        part[t] += p;
        __syncthreads();
    }
    int run = (t == 0) ? 0 : part[t - 1];
#pragma unroll
    for (int i = 0; i < 4; i++) {
        int idx = t * 4 + i;
        if (idx < NBUK) { bucket_off[idx] = run; run += v[i]; }
        else if (idx == NBUK) bucket_off[idx] = run;  // == N_EDGES
    }
    if (t == 0) row_ptr[N_NODES] = N_EDGES;
}

// ---------------- phase 4: deterministic scatter into packed ebin ----------------
// LDS cursors preloaded with exact global positions; zero global atomics.

__global__ __launch_bounds__(256) void k_binA2(const int4* __restrict__ src4,
                                               const int4* __restrict__ dst4,
                                               const int* __restrict__ exc,
                                               const int* __restrict__ bucket_off,
                                               int2* __restrict__ ebin) {
    __shared__ int cur[NBUK];
    int t = threadIdx.x;
    for (int i = t; i < NBUK; i += 256)
        cur[i] = bucket_off[i] + exc[blockIdx.x * NBUK_P + i];
    __syncthreads();
    int idx = blockIdx.x * 256 + t;
    if (idx < N_EDGES / 4) {
        int4 s = src4[idx];
        int4 d = dst4[idx];
        int p0 = atomicAdd(&cur[d.x >> 6], 1);
        int p1 = atomicAdd(&cur[d.y >> 6], 1);
        int p2 = atomicAdd(&cur[d.z >> 6], 1);
        int p3 = atomicAdd(&cur[d.w >> 6], 1);
        ebin[p0] = make_int2(s.x, d.x);
        ebin[p1] = make_int2(s.y, d.y);
        ebin[p2] = make_int2(s.z, d.z);
        ebin[p3] = make_int2(s.w, d.w);
    }
}

// ---------------- per-bucket degree count + node scan -> row_ptr, dinv ----------------
// 4 waves/block, one wave per bucket. LDS counting (no global atomics).
__global__ __launch_bounds__(256) void k_bucket_deg(const int2* __restrict__ ebin,
                                                    const int* __restrict__ bucket_off,
                                                    int* __restrict__ row_ptr,
                                                    float* __restrict__ dinv) {
    __shared__ int cnt[4][64];
    int wave = threadIdx.x >> 6;
    int lane = threadIdx.x & 63;
    int b = blockIdx.x * 4 + wave;
    if (b >= NBUK) return;
    cnt[wave][lane] = 0;
    __syncthreads();
    int base = bucket_off[b];
    int c = bucket_off[b + 1] - base;
    const int2* eb = &ebin[base];
    for (int i = lane; i < c; i += 64) atomicAdd(&cnt[wave][eb[i].y & 63], 1);
    __syncthreads();
    int deg = cnt[wave][lane];
    int sum = deg;
#pragma unroll
    for (int off = 1; off < 64; off <<= 1) {
        int v = __shfl_up(sum, off, 64);
        if (lane >= off) sum += v;
    }
    int node = b * 64 + lane;
    if (node < N_NODES) {
        row_ptr[node] = base + sum - deg;
        dinv[node] = rsqrtf((float)(deg + 1));  // +1 self-loop
    }
}

// ---------------- final: node-sorted records within bucket via LDS cursors ----------------
// rec = (src, dinv[src]); the dinv[dst] factor is applied in the agg kernels.
__global__ __launch_bounds__(256) void k_binB(const int2* __restrict__ ebin,
                                              const int* __restrict__ bucket_off,
                                              const int* __restrict__ row_ptr,
                                              const float* __restrict__ dinv,
                                              int2* __restrict__ rec) {
    __shared__ int cur[64];
    int b = blockIdx.x;
    int tid = threadIdx.x;
    if (tid < 64) {
        int node = b * 64 + tid;
        cur[tid] = (node < N_NODES) ? row_ptr[node] : 0;
    }
    __syncthreads();
    int base = bucket_off[b];
    int c = bucket_off[b + 1] - base;
    const int2* eb = &ebin[base];
    for (int i = tid; i < c; i += 256) {
        int2 e = eb[i];
        float ws = dinv[e.x];
        int pos = atomicAdd(&cur[e.y & 63], 1);
        rec[pos] = make_int2(e.x, __float_as_int(ws));
    }
}

// ---------------- GEMM1: h = x @ W1 ----------------

__device__ inline void fma4(float4& acc, float s, const float4& w) {
    acc.x = fmaf(s, w.x, acc.x);
    acc.y = fmaf(s, w.y, acc.y);
    acc.z = fmaf(s, w.z, acc.z);
    acc.w = fmaf(s, w.w, acc.w);
}

__global__ __launch_bounds__(256) void k_gemm1(
    const float* __restrict__ x, const float* __restrict__ W1, float* __restrict__ h)
{
    __shared__ float Ws[D_IN * HIDDEN];  // [k][col] 32KB
    __shared__ float xs[64 * D_IN];      // [row][k^swz] 32KB
    const int tid = threadIdx.x;
    const int row0 = blockIdx.x * 64;

    const float4* W4 = (const float4*)W1;
    float4* Ws4 = (float4*)Ws;
    for (int i = tid; i < D_IN * HIDDEN / 4; i += 256) Ws4[i] = W4[i];

    for (int i = tid; i < 64 * D_IN / 4; i += 256) {
        int r = i >> 5;
        int k4 = (i & 31) << 2;
        float4 v = make_float4(0.f, 0.f, 0.f, 0.f);
        int grow = row0 + r;
        if (grow < N_NODES) v = *(const float4*)&x[grow * D_IN + k4];
        int sw = ((r >> 2) & 1) << 4;
        *(float4*)&xs[r * D_IN + (k4 ^ sw)] = v;
    }
    __syncthreads();

    const int c4 = (tid & 15) * 4;
    const int r4 = (tid >> 4) * 4;
    float4 acc[4];
#pragma unroll
    for (int j = 0; j < 4; j++) acc[j] = make_float4(0.f, 0.f, 0.f, 0.f);

    for (int k = 0; k < D_IN; k += 4) {
        float4 w0 = *(const float4*)&Ws[(k + 0) * HIDDEN + c4];
        float4 w1 = *(const float4*)&Ws[(k + 1) * HIDDEN + c4];
        float4 w2 = *(const float4*)&Ws[(k + 2) * HIDDEN + c4];
        float4 w3 = *(const float4*)&Ws[(k + 3) * HIDDEN + c4];
        float4 a[4];
#pragma unroll
        for (int j = 0; j < 4; j++) {
            int r = r4 + j;
            int sw = ((r >> 2) & 1) << 4;
            a[j] = *(const float4*)&xs[r * D_IN + (k ^ sw)];
        }
#pragma unroll
        for (int j = 0; j < 4; j++) {
            fma4(acc[j], a[j].x, w0);
            fma4(acc[j], a[j].y, w1);
            fma4(acc[j], a[j].z, w2);
            fma4(acc[j], a[j].w, w3);
        }
    }

#pragma unroll
    for (int j = 0; j < 4; j++) {
        int grow = row0 + r4 + j;
        if (grow < N_NODES) *(float4*)&h[grow * HIDDEN + c4] = acc[j];
    }
}

// ---------------- fused: pull-aggregate layer1 + relu + layer2 + self-loop init ----------------
// acc_total = (sum_e v_e*dinv_src + h_node*di) * di
__global__ __launch_bounds__(256) void k_agg1_l2(
    const float* __restrict__ h, const int* __restrict__ row_ptr,
    const int2* __restrict__ rec, const float* __restrict__ dinv,
    const float* __restrict__ b1, const float* __restrict__ W2,
    const float* __restrict__ b2, float* __restrict__ z, float* __restrict__ out)
{
    int node = blockIdx.x * 4 + (threadIdx.x >> 6);  // grid 12500, exact
    int lane = threadIdx.x & 63;

    float di = dinv[node];
    float acc = h[node * HIDDEN + lane] * di;  // self-loop (x di again at end)

    int beg = row_ptr[node];
    int end = row_ptr[node + 1];

    for (int base = beg; base < end; base += 64) {
        int n = end - base;
        if (n > 64) n = 64;
        int2 r = make_int2(0, 0);  // pad lanes: src=0, w=0 -> harmless fma
        if (lane < n) r = rec[base + lane];
        int n4 = (n + 3) & ~3;
        for (int e = 0; e < n4; e += 4) {
            int   s0 = __shfl(r.x, e + 0, 64);
            float w0 = __int_as_float(__shfl(r.y, e + 0, 64));
            int   s1 = __shfl(r.x, e + 1, 64);
            float w1 = __int_as_float(__shfl(r.y, e + 1, 64));
            int   s2 = __shfl(r.x, e + 2, 64);
            float w2 = __int_as_float(__shfl(r.y, e + 2, 64));
            int   s3 = __shfl(r.x, e + 3, 64);
            float w3 = __int_as_float(__shfl(r.y, e + 3, 64));
            float v0 = h[(size_t)s0 * HIDDEN + lane];
            float v1 = h[(size_t)s1 * HIDDEN + lane];
            float v2 = h[(size_t)s2 * HIDDEN + lane];
            float v3 = h[(size_t)s3 * HIDDEN + lane];
            acc = fmaf(v0, w0, acc);
            acc = fmaf(v1, w1, acc);
            acc = fmaf(v2, w2, acc);
            acc = fmaf(v3, w3, acc);
        }
    }
    acc *= di;

    // layer 2: y = relu(acc + b1); p = y @ W2 (wave-reduce)
    float y = fmaxf(acc + b1[lane], 0.0f);
    float p0 = y * W2[lane * N_CLASSES + 0];
    float p1 = y * W2[lane * N_CLASSES + 1];
#pragma unroll
    for (int off = 32; off > 0; off >>= 1) {
        p0 += __shfl_down(p0, off, 64);
        p1 += __shfl_down(p1, off, 64);
    }
    if (lane == 0) {
        float s2 = di * di;
        z[node * 2 + 0] = p0;
        z[node * 2 + 1] = p1;
        out[node * 2 + 0] = fmaf(p0, s2, b2[0]);  // self-loop + bias init
        out[node * 2 + 1] = fmaf(p1, s2, b2[1]);
    }
}

// ---------------- pull-aggregate layer 2: wave per node, lane-parallel edges ----------------

__global__ __launch_bounds__(256) void k_agg2(
    const float* __restrict__ z, const int* __restrict__ row_ptr,
    const int2* __restrict__ rec, const float* __restrict__ dinv,
    float* __restrict__ out)
{
    int node = blockIdx.x * 4 + (threadIdx.x >> 6);  // grid 12500, exact
    int lane = threadIdx.x & 63;
    int beg = row_ptr[node];
    int end = row_ptr[node + 1];
    float a0 = 0.f, a1 = 0.f;
    for (int idx = beg + lane; idx < end; idx += 64) {
        int2 r = rec[idx];
        float w = __int_as_float(r.y);
        float2 v = *(const float2*)&z[r.x * 2];
        a0 = fmaf(v.x, w, a0);
        a1 = fmaf(v.y, w, a1);
    }
#pragma unroll
    for (int off = 32; off > 0; off >>= 1) {
        a0 += __shfl_down(a0, off, 64);
        a1 += __shfl_down(a1, off, 64);
    }
    if (lane == 0) {
        float di = dinv[node];
        out[node * 2 + 0] += a0 * di;  // out pre-initialized with self-loop + bias
        out[node * 2 + 1] += a1 * di;
    }
}

// ---------------- launch ----------------

extern "C" void kernel_launch(void* const* d_in, const int* in_sizes, int n_in,
                              void* d_out, int out_size, void* d_ws, size_t ws_size,
                              hipStream_t stream) {
    const float* x  = (const float*)d_in[0];
    const int* ei   = (const int*)d_in[1];
    const float* W1 = (const float*)d_in[2];
    const float* b1 = (const float*)d_in[3];
    const float* W2 = (const float*)d_in[4];
    const float* b2 = (const float*)d_in[5];
    float* out = (float*)d_out;

    const int* src = ei;
    const int* dst = ei + N_EDGES;

    // workspace layout (4-byte units), ~24.9 MB total (R1 used 26.2 MB OK)
    int*   bucket_off = (int*)d_ws;                      // [0, 1024)      (783 used)
    int*   colsum     = (int*)d_ws + 1024;               // [1024, 2048)   (782 used)
    float* dinv       = (float*)d_ws + 2048;             // [2048, 52224)
    int*   row_ptr    = (int*)d_ws + 52224;              // [52224, 102400)
    int*   bhist      = (int*)d_ws + 102400;             // 782*784 = 613088 -> pad 613120
    int*   exc        = (int*)d_ws + 715520;             // 613088 -> pad 613120
    int2*  rec        = (int2*)((int*)d_ws + 1328640);   // 800000 int2
    int2*  ebin       = (int2*)((int*)d_ws + 2928640);   // 800000 int2 (aliased by h below)
    float* h          = (float*)d_ws + 2928640;          // 3.2M floats, written after ebin dead
    float* z          = (float*)d_ws + 6128640;          // 100k floats

    k_hist<<<NBLK, 256, 0, stream>>>((const int4*)dst, bhist);
    k_colscan<<<NBUK, 256, 0, stream>>>(bhist, exc, colsum);
    k_bucket_scan<<<1, 256, 0, stream>>>(colsum, bucket_off, row_ptr);
    k_binA2<<<NBLK, 256, 0, stream>>>((const int4*)src, (const int4*)dst, exc, bucket_off, ebin);
    k_bucket_deg<<<(NBUK + 3) / 4, 256, 0, stream>>>(ebin, bucket_off, row_ptr, dinv);
    k_binB<<<NBUK, 256, 0, stream>>>(ebin, bucket_off, row_ptr, dinv, rec);
    k_gemm1<<<(N_NODES + 63) / 64, 256, 0, stream>>>(x, W1, h);
    k_agg1_l2<<<N_NODES / 4, 256, 0, stream>>>(h, row_ptr, rec, dinv, b1, W2, b2, z, out);
    k_agg2<<<N_NODES / 4, 256, 0, stream>>>(z, row_ptr, rec, dinv, out);
}